// Round 16
// baseline (291.207 us; speedup 1.0000x reference)
//
#include <hip/hip_runtime.h>
#include <cstdint>
#include <cstddef>

// ---- types ----
typedef _Float16 f16x8 __attribute__((ext_vector_type(8)));
typedef _Float16 f16x4 __attribute__((ext_vector_type(4)));
typedef float    f32x4 __attribute__((ext_vector_type(4)));
typedef unsigned short ushort_t;

#define LOG2E 1.4426950408889634f

constexpr int BATCH = 2;
constexpr int TSEQ  = 2048;
constexpr int HID   = 2048;
constexpr int NH    = 16;
constexpr int HD    = 128;
constexpr int GK    = 2048;   // K-dim of both GEMMs
constexpr int NKT   = GK / 64; // 32 K-tiles

__device__ inline f32x4 mfma16(f16x8 a, f16x8 b, f32x4 c) {
    return __builtin_amdgcn_mfma_f32_16x16x32_f16(a, b, c, 0, 0, 0);
}

// async global->LDS, 16B per lane; LDS dest must be linear (base + lane*16)
__device__ inline void async_copy16(const void* src, void* dst_lds) {
    __builtin_amdgcn_global_load_lds(
        (const __attribute__((address_space(1))) uint32_t*)src,
        (__attribute__((address_space(3))) uint32_t*)dst_lds, 16, 0, 0);
}

// v_cvt_pkrtz_f16_f32: pack 2 floats to 2 f16 in one u32.
__device__ inline uint32_t pkrtz(float a, float b) {
    union { decltype(__builtin_amdgcn_cvt_pkrtz(0.f, 0.f)) h; uint32_t u; } cv;
    cv.h = __builtin_amdgcn_cvt_pkrtz(a, b);
    return cv.u;
}

// ---- fp32 -> fp16 cast, all three tensors in one launch ----
__global__ __launch_bounds__(256)
void cast_all(const float4* __restrict__ hs, const float4* __restrict__ wqkv,
              const float4* __restrict__ wout, f16x4* __restrict__ hs_h,
              f16x4* __restrict__ wqkv_h, f16x4* __restrict__ wout_h,
              int n_hs, int n_wqkv, int n_wout) {
    int i = blockIdx.x * 256 + threadIdx.x;
    const float4* src; f16x4* dst; int j;
    if (i < n_hs)                 { src = hs;   dst = hs_h;   j = i; }
    else if (i < n_hs + n_wqkv)   { src = wqkv; dst = wqkv_h; j = i - n_hs; }
    else if (i < n_hs + n_wqkv + n_wout) { src = wout; dst = wout_h; j = i - n_hs - n_wqkv; }
    else return;
    float4 v = src[j];
    f16x4 o = { (_Float16)v.x, (_Float16)v.y, (_Float16)v.z, (_Float16)v.w };
    dst[j] = o;
}

// ---- GEMM qkv v2: BM=BN=256, BK=64; 512 thr / 8 waves (2M x 4N), per-wave
// 128x64 (acc[8][4], MFMA:ds_read = 2.67). 2-dbuf LDS (128KB) with phase-split
// progressive reuse: B-reads sealed (lgkm0+barrier) -> stageB(t+2) overwrites
// dead B-half; A-reads sealed at phase 3 -> stageA(t+2). Entry vmcnt(8): only
// tile t+1's loads stay in flight; never drains mid-loop. B-frags reg-cached.
__global__ __launch_bounds__(512)
void gemm_qkv(const _Float16* __restrict__ A, const _Float16* __restrict__ B,
              _Float16* __restrict__ Qo, _Float16* __restrict__ Ko,
              _Float16* __restrict__ Vo) {
    __shared__ __align__(16) _Float16 As[2][256 * 64];  // 32KB x2
    __shared__ __align__(16) _Float16 Bs[2][256 * 64];  // 32KB x2 (128KB total)

    const int tid  = threadIdx.x;
    const int lane = tid & 63;
    const int w    = tid >> 6;
    const int l15  = lane & 15;
    const int lq   = lane >> 4;
    const int wr   = w >> 2;        // 0..1 (M half)
    const int wc   = w & 3;         // 0..3 (N quarter)

    // T1 XCD swizzle; grid 384 (%8==0), cpx=48
    const int bid = (int)blockIdx.x;
    const int swz = (bid & 7) * 48 + (bid >> 3);
    const int bn  = swz % 24, bm = swz / 24;
    const int m0  = bm * 256, n0 = bn * 256;

    const _Float16* Ab = A + (size_t)m0 * GK;
    const _Float16* Bb = B + (size_t)n0 * GK;

    auto stageB = [&](int t, int c) {   // 256 rows x 8 chunks = 4 loads/thread
        const int k0 = t * 64;
        #pragma unroll
        for (int it = 0; it < 4; ++it) {
            const int slot = it * 512 + tid;
            const int row = slot >> 3, c16 = slot & 7;
            const int srcb = c16 ^ (row & 7);           // inverse-swizzled src
            async_copy16(Bb + (size_t)row * GK + k0 + srcb * 8,
                         (char*)Bs[c] + slot * 16);     // linear dest
        }
    };
    auto stageA = [&](int t, int c) {
        const int k0 = t * 64;
        #pragma unroll
        for (int it = 0; it < 4; ++it) {
            const int slot = it * 512 + tid;
            const int row = slot >> 3, c16 = slot & 7;
            const int srcb = c16 ^ (row & 7);
            async_copy16(Ab + (size_t)row * GK + k0 + srcb * 8,
                         (char*)As[c] + slot * 16);
        }
    };

    f32x4 acc[8][4] = {};

    // prologue: uniform B-then-A issue order per tile (vmcnt arithmetic)
    stageB(0, 0); stageA(0, 0);
    stageB(1, 1); stageA(1, 1);

    for (int t = 0; t < NKT; ++t) {
        const int c = t & 1;
        // entry: own tile-t loads landed; tile t+1's 8 remain in flight
        if (t + 1 < NKT) asm volatile("s_waitcnt vmcnt(8)" ::: "memory");
        else             asm volatile("s_waitcnt vmcnt(0)" ::: "memory");
        __builtin_amdgcn_s_barrier();
        __builtin_amdgcn_sched_barrier(0);

        const char* At_ = (const char*)As[c];
        const char* Bt_ = (const char*)Bs[c];

        // ---- phase 0: all B-frags to regs + A-frags M0,M1 ----
        f16x8 bfr[4][2];
        #pragma unroll
        for (int j = 0; j < 4; ++j)
            #pragma unroll
            for (int kk = 0; kk < 2; ++kk) {
                const int rb = wc * 64 + j * 16 + l15;
                bfr[j][kk] = *(const f16x8*)(Bt_ + rb * 128 + (((kk * 4 + lq) ^ (rb & 7)) << 4));
            }
        f16x8 af[2][2];
        #pragma unroll
        for (int i = 0; i < 2; ++i)
            #pragma unroll
            for (int kk = 0; kk < 2; ++kk) {
                const int ra = wr * 128 + i * 16 + l15;
                af[i][kk] = *(const f16x8*)(At_ + ra * 128 + (((kk * 4 + lq) ^ (ra & 7)) << 4));
            }
        asm volatile("s_waitcnt lgkmcnt(0)" ::: "memory");
        __builtin_amdgcn_sched_barrier(0);
        __builtin_amdgcn_s_barrier();          // B-half of buf c is dead block-wide
        __builtin_amdgcn_sched_barrier(0);
        if (t + 2 < NKT) stageB(t + 2, c);     // async overwrite of dead B-half

        __builtin_amdgcn_s_setprio(1);
        #pragma unroll
        for (int kk = 0; kk < 2; ++kk)
            #pragma unroll
            for (int i = 0; i < 2; ++i)
                #pragma unroll
                for (int j = 0; j < 4; ++j)
                    acc[i][j] = mfma16(af[i][kk], bfr[j][kk], acc[i][j]);
        __builtin_amdgcn_s_setprio(0);

        // ---- phases 1,2: M-frags 2..5 (no barriers; A-half untouched) ----
        #pragma unroll
        for (int ph = 1; ph <= 2; ++ph) {
            #pragma unroll
            for (int i = 0; i < 2; ++i)
                #pragma unroll
                for (int kk = 0; kk < 2; ++kk) {
                    const int ra = wr * 128 + (ph * 2 + i) * 16 + l15;
                    af[i][kk] = *(const f16x8*)(At_ + ra * 128 + (((kk * 4 + lq) ^ (ra & 7)) << 4));
                }
            __builtin_amdgcn_s_setprio(1);
            #pragma unroll
            for (int kk = 0; kk < 2; ++kk)
                #pragma unroll
                for (int i = 0; i < 2; ++i)
                    #pragma unroll
                    for (int j = 0; j < 4; ++j)
                        acc[ph * 2 + i][j] = mfma16(af[i][kk], bfr[j][kk], acc[ph * 2 + i][j]);
            __builtin_amdgcn_s_setprio(0);
        }

        // ---- phase 3: M-frags 6,7; then A-half free -> stageA(t+2) ----
        #pragma unroll
        for (int i = 0; i < 2; ++i)
            #pragma unroll
            for (int kk = 0; kk < 2; ++kk) {
                const int ra = wr * 128 + (6 + i) * 16 + l15;
                af[i][kk] = *(const f16x8*)(At_ + ra * 128 + (((kk * 4 + lq) ^ (ra & 7)) << 4));
            }
        asm volatile("s_waitcnt lgkmcnt(0)" ::: "memory");
        __builtin_amdgcn_sched_barrier(0);
        __builtin_amdgcn_s_barrier();          // A-half of buf c is dead block-wide
        __builtin_amdgcn_sched_barrier(0);
        if (t + 2 < NKT) stageA(t + 2, c);

        __builtin_amdgcn_s_setprio(1);
        #pragma unroll
        for (int kk = 0; kk < 2; ++kk)
            #pragma unroll
            for (int i = 0; i < 2; ++i)
                #pragma unroll
                for (int j = 0; j < 4; ++j)
                    acc[6 + i][j] = mfma16(af[i][kk], bfr[j][kk], acc[6 + i][j]);
        __builtin_amdgcn_s_setprio(0);
    }

    // epilogue: scatter to Q/K/V [B][NH][T][HD], Q scaled by 1/sqrt(HD)
    #pragma unroll
    for (int j = 0; j < 4; ++j) {
        const int ncol = n0 + wc * 64 + j * 16 + l15;
        const int which = ncol >> 11;          // 0=Q 1=K 2=V
        const int oo = ncol & 2047;
        const int head = oo >> 7;
        const int d = oo & 127;
        _Float16* dst = (which == 0) ? Qo : (which == 1) ? Ko : Vo;
        const float scl = (which == 0) ? 0.08838834764831845f : 1.0f;
        #pragma unroll
        for (int i = 0; i < 8; ++i) {
            #pragma unroll
            for (int r = 0; r < 4; ++r) {
                const int m = m0 + wr * 128 + i * 16 + lq * 4 + r;
                const int b = m >> 11, tt = m & 2047;
                dst[((size_t)(b * NH + head) * TSEQ + tt) * HD + d] =
                    (_Float16)(acc[i][j][r] * scl);
            }
        }
    }
}

// ---- GEMM small (R8/R9-proven on out-proj): 128^2, 256 thr, 2-ring + vmcnt(8) ----
template <int MODE>
__global__ __launch_bounds__(256, 2)
void gemm_small(const _Float16* __restrict__ A, const _Float16* __restrict__ B,
                float* __restrict__ C, int NB) {
    __shared__ __align__(16) _Float16 As[2][128 * 64];
    __shared__ __align__(16) _Float16 Bs[2][128 * 64];

    const int tid  = threadIdx.x;
    const int lane = tid & 63;
    const int w    = tid >> 6;
    const int l15  = lane & 15;
    const int lq   = lane >> 4;
    const int wr   = w >> 1, wc = w & 1;

    const int bid = (int)blockIdx.x;
    const int cpx = (int)gridDim.x >> 3;
    const int swz = (bid & 7) * cpx + (bid >> 3);
    const int bn  = swz % NB, bm = swz / NB;
    const int m0  = bm * 128, n0 = bn * 128;

    const _Float16* Ab = A + (size_t)m0 * GK;
    const _Float16* Bb = B + (size_t)n0 * GK;

    auto stage = [&](int t, int b) {
        const int k0 = t * 64;
        #pragma unroll
        for (int it = 0; it < 4; ++it) {
            const int slot = it * 256 + tid;
            const int row = slot >> 3, c16 = slot & 7;
            const int srcb = c16 ^ (row & 7);
            async_copy16(Ab + (size_t)row * GK + k0 + srcb * 8,
                         (char*)As[b] + slot * 16);
        }
        #pragma unroll
        for (int it = 0; it < 4; ++it) {
            const int slot = it * 256 + tid;
            const int row = slot >> 3, c16 = slot & 7;
            const int srcb = c16 ^ (row & 7);
            async_copy16(Bb + (size_t)row * GK + k0 + srcb * 8,
                         (char*)Bs[b] + slot * 16);
        }
    };

    f32x4 acc[4][4] = {};

    stage(0, 0);
    stage(1, 1);

    for (int t = 0; t < NKT; ++t) {
        const int cur = t & 1;
        if (t + 1 < NKT) asm volatile("s_waitcnt vmcnt(8)" ::: "memory");
        else             asm volatile("s_waitcnt vmcnt(0)" ::: "memory");
        __builtin_amdgcn_s_barrier();
        __builtin_amdgcn_sched_barrier(0);

        const char* At_ = (const char*)As[cur];
        const char* Bt_ = (const char*)Bs[cur];

        f16x8 af[4][2], bff[4][2];
        #pragma unroll
        for (int i = 0; i < 4; ++i)
            #pragma unroll
            for (int kk = 0; kk < 2; ++kk) {
                const int ra = wr * 64 + i * 16 + l15;
                af[i][kk]  = *(const f16x8*)(At_ + ra * 128 + (((kk * 4 + lq) ^ (ra & 7)) << 4));
                const int rb = wc * 64 + i * 16 + l15;
                bff[i][kk] = *(const f16x8*)(Bt_ + rb * 128 + (((kk * 4 + lq) ^ (rb & 7)) << 4));
            }
        asm volatile("s_waitcnt lgkmcnt(0)" ::: "memory");
        __builtin_amdgcn_sched_barrier(0);
        __builtin_amdgcn_s_barrier();
        __builtin_amdgcn_sched_barrier(0);

        if (t + 2 < NKT) stage(t + 2, cur);

        __builtin_amdgcn_s_setprio(1);
        #pragma unroll
        for (int kk = 0; kk < 2; ++kk)
            #pragma unroll
            for (int i = 0; i < 4; ++i)
                #pragma unroll
                for (int j = 0; j < 4; ++j)
                    acc[i][j] = mfma16(af[i][kk], bff[j][kk], acc[i][j]);
        __builtin_amdgcn_s_setprio(0);
    }

    #pragma unroll
    for (int i = 0; i < 4; ++i)
        #pragma unroll
        for (int j = 0; j < 4; ++j)
            #pragma unroll
            for (int r = 0; r < 4; ++r) {
                const int m = m0 + wr * 64 + i * 16 + lq * 4 + r;
                const int n = n0 + wc * 64 + j * 16 + l15;
                C[(size_t)m * HID + n] = acc[i][j][r];
            }
}

// ---- causal flash attention v7 (R11-proven local optimum) ----
__global__ __launch_bounds__(256)
void attn_fwd(const _Float16* __restrict__ Q, const _Float16* __restrict__ K,
              const _Float16* __restrict__ V, _Float16* __restrict__ O) {
    __shared__ __align__(16) char Ks[64 * 256];   // [64][128] f16, swizzled (16KB)
    __shared__ __align__(16) char Vt[128 * 128];  // [128][64] f16 V^T, swizzled (16KB)

    const int tid  = threadIdx.x;
    const int lane = tid & 63;
    const int w    = tid >> 6;      // 0..3
    const int l15  = lane & 15;
    const int lq   = lane >> 4;
    const int lq1  = lq >> 1;                      // 0,0,1,1
    const int laneA = l15 + ((lane & 16) << 1);    // l15 + 32*(lq&1)
    const int laneB = laneA + 16;

    const int bh   = (int)blockIdx.x & 31;   // same-bh blocks share XCD (bid&7=bh&7)
    const int pair = (int)blockIdx.x >> 5;   // 0..15
    const int b = bh >> 4, h = bh & 15;

    const size_t base = (size_t)bh * TSEQ * HD;
    const _Float16* Qp = Q + base;
    const _Float16* Kp = K + base;
    const _Float16* Vp = V + base;

    uint4 vv[4];
    auto loadV = [&](int t) {   // lane = kv row; wave w owns d-chunks w*4..w*4+3
        const int row = tid & 63;
        #pragma unroll
        for (int it = 0; it < 4; ++it) {
            const int c8 = w * 4 + it;
            vv[it] = *(const uint4*)(Vp + (size_t)(t * 64 + row) * HD + c8 * 8);
        }
    };
    auto stageK = [&](int t) {
        #pragma unroll
        for (int it = 0; it < 4; ++it) {
            const int slot = it * 256 + tid;
            const int row = slot >> 4, c16 = slot & 15;
            const int srcb = c16 ^ (row & 7);
            async_copy16(Kp + (size_t)(t * 64 + row) * HD + srcb * 8, Ks + slot * 16);
        }
    };
    auto writeV = [&]() {   // ushort stores at d*128 + row*2: 2-way, free
        const int row = tid & 63;
        #pragma unroll
        for (int it = 0; it < 4; ++it) {
            const int c8 = w * 4 + it;
            const uint32_t wrd[4] = {vv[it].x, vv[it].y, vv[it].z, vv[it].w};
            #pragma unroll
            for (int p2 = 0; p2 < 4; ++p2) {
                const int d0 = c8 * 8 + p2 * 2, d1 = d0 + 1;
                int b0 = d0 * 128 + row * 2; b0 ^= (d0 & 7) << 4;
                int b1 = d1 * 128 + row * 2; b1 ^= (d1 & 7) << 4;
                *(ushort_t*)(Vt + b0) = (ushort_t)(wrd[p2] & 0xffffu);
                *(ushort_t*)(Vt + b1) = (ushort_t)(wrd[p2] >> 16);
            }
        }
    };

    for (int phase = 0; phase < 2; ++phase) {
        const int qt = phase ? pair : (31 - pair);
        const int q0 = qt * 64;
        const int NT = qt + 1;

        if (phase) __syncthreads();

        const int qrow = q0 + w * 16 + l15;
        f16x8 qf[4];
        #pragma unroll
        for (int ks = 0; ks < 4; ++ks)
            qf[ks] = *(const f16x8*)(Qp + (size_t)qrow * HD + ks * 32 + lq * 8);

        f32x4 o[8] = {};
        float m_run = -1e30f;
        float osum  = 0.0f;

        stageK(0);
        loadV(0);

        for (int t = 0; t < NT; ++t) {
            writeV();
            __syncthreads();      // barrier B: stageK(t) drained + writeV visible
            if (t + 1 < NT) loadV(t + 1);

            const int kv0 = t * 64;
            f32x4 s[4] = {};
            __builtin_amdgcn_s_setprio(1);
            #pragma unroll
            for (int ks = 0; ks < 4; ++ks) {
                #pragma unroll
                for (int nf = 0; nf < 4; ++nf) {
                    const int r   = nf * 16 + l15;
                    const int blk = (ks * 4 + lq) ^ (r & 7);
                    const f16x8 kf = *(const f16x8*)(Ks + r * 256 + blk * 16);
                    s[nf] = mfma16(kf, qf[ks], s[nf]);   // swapped operands
                }
            }
            __builtin_amdgcn_s_setprio(0);

            if (kv0 + 63 > q0 + w * 16) {
                const int q_lane = q0 + w * 16 + l15;
                #pragma unroll
                for (int nf = 0; nf < 4; ++nf) {
                    #pragma unroll
                    for (int r = 0; r < 4; ++r) {
                        const int kv = kv0 + nf * 16 + lq * 4 + r;
                        if (kv > q_lane) s[nf][r] = -1e30f;
                    }
                }
            }

            float lmax = -1e30f;
            #pragma unroll
            for (int nf = 0; nf < 4; ++nf)
                lmax = fmaxf(lmax, fmaxf(fmaxf(s[nf][0], s[nf][1]),
                                         fmaxf(s[nf][2], s[nf][3])));
            if (__any(lmax > m_run + 5.0f)) {
                float v = lmax;
                v = fmaxf(v, __shfl_xor(v, 16));
                v = fmaxf(v, __shfl_xor(v, 32));
                const float mn = fmaxf(m_run, v);
                const float alpha = __builtin_exp2f((m_run - mn) * LOG2E);
                m_run = mn;
                osum *= alpha;
                float aq[4];
                #pragma unroll
                for (int r = 0; r < 4; ++r)
                    aq[r] = __shfl(alpha, lq * 4 + r);
                #pragma unroll
                for (int df = 0; df < 8; ++df)
                    #pragma unroll
                    for (int r = 0; r < 4; ++r)
                        o[df][r] *= aq[r];
            }

            uint32_t pk[4][2];
            float psum = 0.0f;
            #pragma unroll
            for (int nf = 0; nf < 4; ++nf) {
                #pragma unroll
                for (int hh = 0; hh < 2; ++hh) {
                    const float pa = __builtin_exp2f((s[nf][2 * hh]     - m_run) * LOG2E);
                    const float pb = __builtin_exp2f((s[nf][2 * hh + 1] - m_run) * LOG2E);
                    psum += pa + pb;
                    pk[nf][hh] = pkrtz(pa, pb);
                }
            }
            osum += psum;

            f16x8 pf[2];
            #pragma unroll
            for (int ks2 = 0; ks2 < 2; ++ks2) {
                union { uint32_t u[4]; f16x8 v; } pu;
                const uint32_t a0n0 = (uint32_t)__shfl((int)pk[2 * ks2][0],     laneA);
                const uint32_t a0n1 = (uint32_t)__shfl((int)pk[2 * ks2 + 1][0], laneA);
                const uint32_t a1n0 = (uint32_t)__shfl((int)pk[2 * ks2][1],     laneA);
                const uint32_t a1n1 = (uint32_t)__shfl((int)pk[2 * ks2 + 1][1], laneA);
                const uint32_t b0n0 = (uint32_t)__shfl((int)pk[2 * ks2][0],     laneB);
                const uint32_t b0n1 = (uint32_t)__shfl((int)pk[2 * ks2 + 1][0], laneB);
                const uint32_t b1n0 = (uint32_t)__shfl((int)pk[2 * ks2][1],     laneB);
                const uint32_t b1n1 = (uint32_t)__shfl((int)pk[2 * ks2 + 1][1], laneB);
                pu.u[0] = lq1 ? a0n1 : a0n0;
                pu.u[1] = lq1 ? a1n1 : a1n0;
                pu.u[2] = lq1 ? b0n1 : b0n0;
                pu.u[3] = lq1 ? b1n1 : b1n0;
                pf[ks2] = pu.v;
            }

            __builtin_amdgcn_s_setprio(1);
            #pragma unroll
            for (int ks2 = 0; ks2 < 2; ++ks2) {
                #pragma unroll
                for (int df = 0; df < 8; ++df) {
                    const int vr   = df * 16 + l15;
                    const int vblk = (ks2 * 4 + lq) ^ (vr & 7);
                    const f16x8 vf = *(const f16x8*)(Vt + vr * 128 + vblk * 16);
                    o[df] = mfma16(pf[ks2], vf, o[df]);
                }
            }
            __builtin_amdgcn_s_setprio(0);

            if (t + 1 < NT) {
                __syncthreads();     // barrier A: all waves done reading Ks/Vt(t)
                stageK(t + 1);
            }
        }

        float tot = osum;
        tot += __shfl_xor(tot, 16);
        tot += __shfl_xor(tot, 32);
        const float rl = 1.0f / tot;
        float rlq[4];
        #pragma unroll
        for (int r = 0; r < 4; ++r)
            rlq[r] = __shfl(rl, lq * 4 + r);

        #pragma unroll
        for (int df = 0; df < 8; ++df) {
            #pragma unroll
            for (int r = 0; r < 4; ++r) {
                const int qg = q0 + w * 16 + lq * 4 + r;
                const int dg = df * 16 + l15;
                O[((size_t)(b * TSEQ + qg)) * HID + h * HD + dg] =
                    (_Float16)(o[df][r] * rlq[r]);
            }
        }
    }
}

extern "C" void kernel_launch(void* const* d_in, const int* in_sizes, int n_in,
                              void* d_out, int out_size, void* d_ws, size_t ws_size,
                              hipStream_t stream) {
    (void)in_sizes; (void)n_in; (void)out_size; (void)ws_size;
    const float* hs   = (const float*)d_in[0];
    const float* wqkv = (const float*)d_in[1];
    const float* wout = (const float*)d_in[2];

    char* ws = (char*)d_ws;
    size_t off = 0;
    _Float16* hs_h   = (_Float16*)(ws + off); off += (size_t)BATCH * TSEQ * HID * 2;
    _Float16* wqkv_h = (_Float16*)(ws + off); off += (size_t)3 * HID * HID * 2;
    _Float16* wout_h = (_Float16*)(ws + off); off += (size_t)HID * HID * 2;
    _Float16* Qh     = (_Float16*)(ws + off); off += (size_t)BATCH * NH * TSEQ * HD * 2;
    _Float16* Kh     = (_Float16*)(ws + off); off += (size_t)BATCH * NH * TSEQ * HD * 2;
    _Float16* Vh     = (_Float16*)(ws + off); off += (size_t)BATCH * NH * TSEQ * HD * 2;
    _Float16* At     = (_Float16*)(ws + off); off += (size_t)BATCH * TSEQ * HID * 2;

    const int n4_hs   = BATCH * TSEQ * HID / 4;
    const int n4_wqkv = 3 * HID * HID / 4;
    const int n4_wout = HID * HID / 4;
    const int n4_all  = n4_hs + n4_wqkv + n4_wout;
    cast_all<<<dim3((n4_all + 255) / 256), dim3(256), 0, stream>>>(
        (const float4*)hs, (const float4*)wqkv, (const float4*)wout,
        (f16x4*)hs_h, (f16x4*)wqkv_h, (f16x4*)wout_h, n4_hs, n4_wqkv, n4_wout);

    // GEMM1: M=4096, N=6144: 256^2 tiles -> grid 16x24 = 384 blocks
    gemm_qkv<<<dim3(384), dim3(512), 0, stream>>>(hs_h, wqkv_h, Qh, Kh, Vh);

    attn_fwd<<<dim3(512), dim3(256), 0, stream>>>(Qh, Kh, Vh, At);

    // GEMM2: M=4096, N=2048: 128^2 -> grid 32x16 = 512 blocks
    gemm_small<1><<<dim3(512), dim3(256), 0, stream>>>(
        At, wout_h, (float*)d_out, 16);
}

// Round 17
// 263.534 us; speedup vs baseline: 1.1050x; 1.1050x over previous
//
#include <hip/hip_runtime.h>
#include <cstdint>
#include <cstddef>

// ---- types ----
typedef _Float16 f16x8 __attribute__((ext_vector_type(8)));
typedef _Float16 f16x4 __attribute__((ext_vector_type(4)));
typedef float    f32x4 __attribute__((ext_vector_type(4)));
typedef unsigned short ushort_t;

#define LOG2E 1.4426950408889634f

constexpr int BATCH = 2;
constexpr int TSEQ  = 2048;
constexpr int HID   = 2048;
constexpr int NH    = 16;
constexpr int HD    = 128;
constexpr int GK    = 2048;   // K-dim of both GEMMs
constexpr int NKT   = GK / 64; // 32 K-tiles

__device__ inline f32x4 mfma16(f16x8 a, f16x8 b, f32x4 c) {
    return __builtin_amdgcn_mfma_f32_16x16x32_f16(a, b, c, 0, 0, 0);
}

// async global->LDS, 16B per lane; LDS dest must be linear (base + lane*16)
__device__ inline void async_copy16(const void* src, void* dst_lds) {
    __builtin_amdgcn_global_load_lds(
        (const __attribute__((address_space(1))) uint32_t*)src,
        (__attribute__((address_space(3))) uint32_t*)dst_lds, 16, 0, 0);
}

// v_cvt_pkrtz_f16_f32: pack 2 floats to 2 f16 in one u32.
__device__ inline uint32_t pkrtz(float a, float b) {
    union { decltype(__builtin_amdgcn_cvt_pkrtz(0.f, 0.f)) h; uint32_t u; } cv;
    cv.h = __builtin_amdgcn_cvt_pkrtz(a, b);
    return cv.u;
}

// ---- fp32 -> fp16 cast, all three tensors in one launch ----
__global__ __launch_bounds__(256)
void cast_all(const float4* __restrict__ hs, const float4* __restrict__ wqkv,
              const float4* __restrict__ wout, f16x4* __restrict__ hs_h,
              f16x4* __restrict__ wqkv_h, f16x4* __restrict__ wout_h,
              int n_hs, int n_wqkv, int n_wout) {
    int i = blockIdx.x * 256 + threadIdx.x;
    const float4* src; f16x4* dst; int j;
    if (i < n_hs)                 { src = hs;   dst = hs_h;   j = i; }
    else if (i < n_hs + n_wqkv)   { src = wqkv; dst = wqkv_h; j = i - n_hs; }
    else if (i < n_hs + n_wqkv + n_wout) { src = wout; dst = wout_h; j = i - n_hs - n_wqkv; }
    else return;
    float4 v = src[j];
    f16x4 o = { (_Float16)v.x, (_Float16)v.y, (_Float16)v.z, (_Float16)v.w };
    dst[j] = o;
}

// ---- GEMM big (R7/R9/R15-proven, 110 µs on qkv-proj): BM=256, BN=128, BK=64;
// 512 thr / 8 waves; 3-ring LDS + counted vmcnt(6); T2 swizzle; T1 XCD swizzle.
template <int MODE>
__global__ __launch_bounds__(512, 2)
void gemm_big(const _Float16* __restrict__ A, const _Float16* __restrict__ B,
              float* __restrict__ C, _Float16* __restrict__ Qo,
              _Float16* __restrict__ Ko, _Float16* __restrict__ Vo, int NB) {
    __shared__ __align__(16) _Float16 As[3][256 * 64];
    __shared__ __align__(16) _Float16 Bs[3][128 * 64];

    const int tid  = threadIdx.x;
    const int lane = tid & 63;
    const int w    = tid >> 6;
    const int l15  = lane & 15;
    const int lq   = lane >> 4;
    const int wr   = w >> 1, wc = w & 1;

    const int bid = (int)blockIdx.x;
    const int cpx = (int)gridDim.x >> 3;
    const int swz = (bid & 7) * cpx + (bid >> 3);
    const int bn  = swz % NB, bm = swz / NB;
    const int m0  = bm * 256, n0 = bn * 128;

    const _Float16* Ab = A + (size_t)m0 * GK;
    const _Float16* Bb = B + (size_t)n0 * GK;

    auto stage = [&](int t, int b) {
        const int k0 = t * 64;
        #pragma unroll
        for (int it = 0; it < 4; ++it) {
            const int slot = it * 512 + tid;
            const int row = slot >> 3, c16 = slot & 7;
            const int srcb = c16 ^ (row & 7);
            async_copy16(Ab + (size_t)row * GK + k0 + srcb * 8,
                         (char*)As[b] + slot * 16);
        }
        #pragma unroll
        for (int it = 0; it < 2; ++it) {
            const int slot = it * 512 + tid;
            const int row = slot >> 3, c16 = slot & 7;
            const int srcb = c16 ^ (row & 7);
            async_copy16(Bb + (size_t)row * GK + k0 + srcb * 8,
                         (char*)Bs[b] + slot * 16);
        }
    };

    f32x4 acc[4][4] = {};

    stage(0, 0);
    stage(1, 1);

    for (int t = 0; t < NKT; ++t) {
        if (t + 1 < NKT) asm volatile("s_waitcnt vmcnt(6)" ::: "memory");
        else             asm volatile("s_waitcnt vmcnt(0)" ::: "memory");
        __builtin_amdgcn_s_barrier();
        __builtin_amdgcn_sched_barrier(0);

        const char* At_ = (const char*)As[t % 3];
        const char* Bt_ = (const char*)Bs[t % 3];

        f16x8 af[4][2], bff[4][2];
        #pragma unroll
        for (int i = 0; i < 4; ++i)
            #pragma unroll
            for (int kk = 0; kk < 2; ++kk) {
                const int ra = wr * 64 + i * 16 + l15;
                af[i][kk]  = *(const f16x8*)(At_ + ra * 128 + (((kk * 4 + lq) ^ (ra & 7)) << 4));
                const int rb = wc * 64 + i * 16 + l15;
                bff[i][kk] = *(const f16x8*)(Bt_ + rb * 128 + (((kk * 4 + lq) ^ (rb & 7)) << 4));
            }

        if (t + 2 < NKT) stage(t + 2, (t + 2) % 3);

        __builtin_amdgcn_s_setprio(1);
        #pragma unroll
        for (int kk = 0; kk < 2; ++kk)
            #pragma unroll
            for (int i = 0; i < 4; ++i)
                #pragma unroll
                for (int j = 0; j < 4; ++j)
                    acc[i][j] = mfma16(af[i][kk], bff[j][kk], acc[i][j]);
        __builtin_amdgcn_s_setprio(0);
    }

    if (MODE == 0) {
        #pragma unroll
        for (int j = 0; j < 4; ++j) {
            const int ncol = n0 + wc * 64 + j * 16 + l15;
            const int which = ncol >> 11;
            const int oo = ncol & 2047;
            const int head = oo >> 7;
            const int d = oo & 127;
            _Float16* dst = (which == 0) ? Qo : (which == 1) ? Ko : Vo;
            const float scl = (which == 0) ? 0.08838834764831845f : 1.0f;
            #pragma unroll
            for (int i = 0; i < 4; ++i) {
                #pragma unroll
                for (int r = 0; r < 4; ++r) {
                    const int m = m0 + wr * 64 + i * 16 + lq * 4 + r;
                    const int b = m >> 11, tt = m & 2047;
                    dst[((size_t)(b * NH + head) * TSEQ + tt) * HD + d] =
                        (_Float16)(acc[i][j][r] * scl);
                }
            }
        }
    } else {
        #pragma unroll
        for (int i = 0; i < 4; ++i)
            #pragma unroll
            for (int j = 0; j < 4; ++j)
                #pragma unroll
                for (int r = 0; r < 4; ++r) {
                    const int m = m0 + wr * 64 + i * 16 + lq * 4 + r;
                    const int n = n0 + wc * 64 + j * 16 + l15;
                    C[(size_t)m * HID + n] = acc[i][j][r];
                }
    }
}

// ---- GEMM small (R8/R9-proven on out-proj): 128^2, 256 thr, 2-ring + vmcnt(8) ----
template <int MODE>
__global__ __launch_bounds__(256, 2)
void gemm_small(const _Float16* __restrict__ A, const _Float16* __restrict__ B,
                float* __restrict__ C, int NB) {
    __shared__ __align__(16) _Float16 As[2][128 * 64];
    __shared__ __align__(16) _Float16 Bs[2][128 * 64];

    const int tid  = threadIdx.x;
    const int lane = tid & 63;
    const int w    = tid >> 6;
    const int l15  = lane & 15;
    const int lq   = lane >> 4;
    const int wr   = w >> 1, wc = w & 1;

    const int bid = (int)blockIdx.x;
    const int cpx = (int)gridDim.x >> 3;
    const int swz = (bid & 7) * cpx + (bid >> 3);
    const int bn  = swz % NB, bm = swz / NB;
    const int m0  = bm * 128, n0 = bn * 128;

    const _Float16* Ab = A + (size_t)m0 * GK;
    const _Float16* Bb = B + (size_t)n0 * GK;

    auto stage = [&](int t, int b) {
        const int k0 = t * 64;
        #pragma unroll
        for (int it = 0; it < 4; ++it) {
            const int slot = it * 256 + tid;
            const int row = slot >> 3, c16 = slot & 7;
            const int srcb = c16 ^ (row & 7);
            async_copy16(Ab + (size_t)row * GK + k0 + srcb * 8,
                         (char*)As[b] + slot * 16);
        }
        #pragma unroll
        for (int it = 0; it < 4; ++it) {
            const int slot = it * 256 + tid;
            const int row = slot >> 3, c16 = slot & 7;
            const int srcb = c16 ^ (row & 7);
            async_copy16(Bb + (size_t)row * GK + k0 + srcb * 8,
                         (char*)Bs[b] + slot * 16);
        }
    };

    f32x4 acc[4][4] = {};

    stage(0, 0);
    stage(1, 1);

    for (int t = 0; t < NKT; ++t) {
        const int cur = t & 1;
        if (t + 1 < NKT) asm volatile("s_waitcnt vmcnt(8)" ::: "memory");
        else             asm volatile("s_waitcnt vmcnt(0)" ::: "memory");
        __builtin_amdgcn_s_barrier();
        __builtin_amdgcn_sched_barrier(0);

        const char* At_ = (const char*)As[cur];
        const char* Bt_ = (const char*)Bs[cur];

        f16x8 af[4][2], bff[4][2];
        #pragma unroll
        for (int i = 0; i < 4; ++i)
            #pragma unroll
            for (int kk = 0; kk < 2; ++kk) {
                const int ra = wr * 64 + i * 16 + l15;
                af[i][kk]  = *(const f16x8*)(At_ + ra * 128 + (((kk * 4 + lq) ^ (ra & 7)) << 4));
                const int rb = wc * 64 + i * 16 + l15;
                bff[i][kk] = *(const f16x8*)(Bt_ + rb * 128 + (((kk * 4 + lq) ^ (rb & 7)) << 4));
            }
        asm volatile("s_waitcnt lgkmcnt(0)" ::: "memory");
        __builtin_amdgcn_sched_barrier(0);
        __builtin_amdgcn_s_barrier();
        __builtin_amdgcn_sched_barrier(0);

        if (t + 2 < NKT) stage(t + 2, cur);

        __builtin_amdgcn_s_setprio(1);
        #pragma unroll
        for (int kk = 0; kk < 2; ++kk)
            #pragma unroll
            for (int i = 0; i < 4; ++i)
                #pragma unroll
                for (int j = 0; j < 4; ++j)
                    acc[i][j] = mfma16(af[i][kk], bff[j][kk], acc[i][j]);
        __builtin_amdgcn_s_setprio(0);
    }

    #pragma unroll
    for (int i = 0; i < 4; ++i)
        #pragma unroll
        for (int j = 0; j < 4; ++j)
            #pragma unroll
            for (int r = 0; r < 4; ++r) {
                const int m = m0 + wr * 64 + i * 16 + lq * 4 + r;
                const int n = n0 + wc * 64 + j * 16 + l15;
                C[(size_t)m * HID + n] = acc[i][j][r];
            }
}

// ---- causal flash attention v7 (R11/R15-proven local optimum) ----
// 512 paired blocks (triangle pairs 31-p/p, uniform 33 kv-tiles), 4 waves.
// Swapped QK^T (S^T = mfma(K,Q)), in-register P (cvt_pkrtz + shfl exchange),
// per-lane scalar softmax state, single-buffered 32KB LDS, 2 barriers/tile.
__global__ __launch_bounds__(256)
void attn_fwd(const _Float16* __restrict__ Q, const _Float16* __restrict__ K,
              const _Float16* __restrict__ V, _Float16* __restrict__ O) {
    __shared__ __align__(16) char Ks[64 * 256];   // [64][128] f16, swizzled (16KB)
    __shared__ __align__(16) char Vt[128 * 128];  // [128][64] f16 V^T, swizzled (16KB)

    const int tid  = threadIdx.x;
    const int lane = tid & 63;
    const int w    = tid >> 6;      // 0..3
    const int l15  = lane & 15;
    const int lq   = lane >> 4;
    const int lq1  = lq >> 1;                      // 0,0,1,1
    const int laneA = l15 + ((lane & 16) << 1);    // l15 + 32*(lq&1)
    const int laneB = laneA + 16;

    const int bh   = (int)blockIdx.x & 31;   // same-bh blocks share XCD (bid&7=bh&7)
    const int pair = (int)blockIdx.x >> 5;   // 0..15
    const int b = bh >> 4, h = bh & 15;

    const size_t base = (size_t)bh * TSEQ * HD;
    const _Float16* Qp = Q + base;
    const _Float16* Kp = K + base;
    const _Float16* Vp = V + base;

    uint4 vv[4];
    auto loadV = [&](int t) {   // lane = kv row; wave w owns d-chunks w*4..w*4+3
        const int row = tid & 63;
        #pragma unroll
        for (int it = 0; it < 4; ++it) {
            const int c8 = w * 4 + it;
            vv[it] = *(const uint4*)(Vp + (size_t)(t * 64 + row) * HD + c8 * 8);
        }
    };
    auto stageK = [&](int t) {
        #pragma unroll
        for (int it = 0; it < 4; ++it) {
            const int slot = it * 256 + tid;
            const int row = slot >> 4, c16 = slot & 15;
            const int srcb = c16 ^ (row & 7);
            async_copy16(Kp + (size_t)(t * 64 + row) * HD + srcb * 8, Ks + slot * 16);
        }
    };
    auto writeV = [&]() {   // ushort stores at d*128 + row*2: 2-way, free
        const int row = tid & 63;
        #pragma unroll
        for (int it = 0; it < 4; ++it) {
            const int c8 = w * 4 + it;
            const uint32_t wrd[4] = {vv[it].x, vv[it].y, vv[it].z, vv[it].w};
            #pragma unroll
            for (int p2 = 0; p2 < 4; ++p2) {
                const int d0 = c8 * 8 + p2 * 2, d1 = d0 + 1;
                int b0 = d0 * 128 + row * 2; b0 ^= (d0 & 7) << 4;
                int b1 = d1 * 128 + row * 2; b1 ^= (d1 & 7) << 4;
                *(ushort_t*)(Vt + b0) = (ushort_t)(wrd[p2] & 0xffffu);
                *(ushort_t*)(Vt + b1) = (ushort_t)(wrd[p2] >> 16);
            }
        }
    };

    for (int phase = 0; phase < 2; ++phase) {
        const int qt = phase ? pair : (31 - pair);
        const int q0 = qt * 64;
        const int NT = qt + 1;

        if (phase) __syncthreads();

        const int qrow = q0 + w * 16 + l15;
        f16x8 qf[4];
        #pragma unroll
        for (int ks = 0; ks < 4; ++ks)
            qf[ks] = *(const f16x8*)(Qp + (size_t)qrow * HD + ks * 32 + lq * 8);

        f32x4 o[8] = {};
        float m_run = -1e30f;
        float osum  = 0.0f;          // per-lane partial (this lane's kv slice, q=l15)

        stageK(0);
        loadV(0);

        for (int t = 0; t < NT; ++t) {
            writeV();
            __syncthreads();      // barrier B: stageK(t) drained + writeV visible
            if (t + 1 < NT) loadV(t + 1);

            const int kv0 = t * 64;
            // S^T = K Q^T : lane holds kv rows (nf*16+lq*4+r), q col = l15
            f32x4 s[4] = {};
            __builtin_amdgcn_s_setprio(1);
            #pragma unroll
            for (int ks = 0; ks < 4; ++ks) {
                #pragma unroll
                for (int nf = 0; nf < 4; ++nf) {
                    const int r   = nf * 16 + l15;
                    const int blk = (ks * 4 + lq) ^ (r & 7);
                    const f16x8 kf = *(const f16x8*)(Ks + r * 256 + blk * 16);
                    s[nf] = mfma16(kf, qf[ks], s[nf]);   // swapped operands
                }
            }
            __builtin_amdgcn_s_setprio(0);

            if (kv0 + 63 > q0 + w * 16) {   // diagonal-crossing for this wave
                const int q_lane = q0 + w * 16 + l15;
                #pragma unroll
                for (int nf = 0; nf < 4; ++nf) {
                    #pragma unroll
                    for (int r = 0; r < 4; ++r) {
                        const int kv = kv0 + nf * 16 + lq * 4 + r;
                        if (kv > q_lane) s[nf][r] = -1e30f;
                    }
                }
            }

            // lazy max (per-lane scalar, q = l15)
            float lmax = -1e30f;
            #pragma unroll
            for (int nf = 0; nf < 4; ++nf)
                lmax = fmaxf(lmax, fmaxf(fmaxf(s[nf][0], s[nf][1]),
                                         fmaxf(s[nf][2], s[nf][3])));
            if (__any(lmax > m_run + 5.0f)) {
                float v = lmax;
                v = fmaxf(v, __shfl_xor(v, 16));
                v = fmaxf(v, __shfl_xor(v, 32));      // all lq copies of q agree
                const float mn = fmaxf(m_run, v);
                const float alpha = __builtin_exp2f((m_run - mn) * LOG2E);
                m_run = mn;
                osum *= alpha;
                float aq[4];
                #pragma unroll
                for (int r = 0; r < 4; ++r)
                    aq[r] = __shfl(alpha, lq * 4 + r);  // alpha for q-row lq*4+r
                #pragma unroll
                for (int df = 0; df < 8; ++df)
                    #pragma unroll
                    for (int r = 0; r < 4; ++r)
                        o[df][r] *= aq[r];
            }

            // P = exp(S - m): pack to f16 pairs in-register
            uint32_t pk[4][2];
            float psum = 0.0f;
            #pragma unroll
            for (int nf = 0; nf < 4; ++nf) {
                #pragma unroll
                for (int hh = 0; hh < 2; ++hh) {
                    const float pa = __builtin_exp2f((s[nf][2 * hh]     - m_run) * LOG2E);
                    const float pb = __builtin_exp2f((s[nf][2 * hh + 1] - m_run) * LOG2E);
                    psum += pa + pb;
                    pk[nf][hh] = pkrtz(pa, pb);
                }
            }
            osum += psum;

            // exchange: build PV A-frags pf[ks2] (P[q=l15][kv=ks2*32+lq*8+j])
            f16x8 pf[2];
            #pragma unroll
            for (int ks2 = 0; ks2 < 2; ++ks2) {
                union { uint32_t u[4]; f16x8 v; } pu;
                const uint32_t a0n0 = (uint32_t)__shfl((int)pk[2 * ks2][0],     laneA);
                const uint32_t a0n1 = (uint32_t)__shfl((int)pk[2 * ks2 + 1][0], laneA);
                const uint32_t a1n0 = (uint32_t)__shfl((int)pk[2 * ks2][1],     laneA);
                const uint32_t a1n1 = (uint32_t)__shfl((int)pk[2 * ks2 + 1][1], laneA);
                const uint32_t b0n0 = (uint32_t)__shfl((int)pk[2 * ks2][0],     laneB);
                const uint32_t b0n1 = (uint32_t)__shfl((int)pk[2 * ks2 + 1][0], laneB);
                const uint32_t b1n0 = (uint32_t)__shfl((int)pk[2 * ks2][1],     laneB);
                const uint32_t b1n1 = (uint32_t)__shfl((int)pk[2 * ks2 + 1][1], laneB);
                pu.u[0] = lq1 ? a0n1 : a0n0;
                pu.u[1] = lq1 ? a1n1 : a1n0;
                pu.u[2] = lq1 ? b0n1 : b0n0;
                pu.u[3] = lq1 ? b1n1 : b1n0;
                pf[ks2] = pu.v;
            }

            // O += P @ V
            __builtin_amdgcn_s_setprio(1);
            #pragma unroll
            for (int ks2 = 0; ks2 < 2; ++ks2) {
                #pragma unroll
                for (int df = 0; df < 8; ++df) {
                    const int vr   = df * 16 + l15;
                    const int vblk = (ks2 * 4 + lq) ^ (vr & 7);
                    const f16x8 vf = *(const f16x8*)(Vt + vr * 128 + vblk * 16);
                    o[df] = mfma16(pf[ks2], vf, o[df]);
                }
            }
            __builtin_amdgcn_s_setprio(0);

            if (t + 1 < NT) {
                __syncthreads();     // barrier A: all waves done reading Ks/Vt(t)
                stageK(t + 1);       // async overwrite of Ks; drains at next barrier B
            }
        }

        // combine partial sums across lq (all share the same m history)
        float tot = osum;
        tot += __shfl_xor(tot, 16);
        tot += __shfl_xor(tot, 32);
        const float rl = 1.0f / tot;           // valid at lane with q = l15
        float rlq[4];
        #pragma unroll
        for (int r = 0; r < 4; ++r)
            rlq[r] = __shfl(rl, lq * 4 + r);   // 1/sum for q-row lq*4+r

        #pragma unroll
        for (int df = 0; df < 8; ++df) {
            #pragma unroll
            for (int r = 0; r < 4; ++r) {
                const int qg = q0 + w * 16 + lq * 4 + r;
                const int dg = df * 16 + l15;
                O[((size_t)(b * TSEQ + qg)) * HID + h * HD + dg] =
                    (_Float16)(o[df][r] * rlq[r]);
            }
        }
    }
}

extern "C" void kernel_launch(void* const* d_in, const int* in_sizes, int n_in,
                              void* d_out, int out_size, void* d_ws, size_t ws_size,
                              hipStream_t stream) {
    (void)in_sizes; (void)n_in; (void)out_size; (void)ws_size;
    const float* hs   = (const float*)d_in[0];
    const float* wqkv = (const float*)d_in[1];
    const float* wout = (const float*)d_in[2];

    char* ws = (char*)d_ws;
    size_t off = 0;
    _Float16* hs_h   = (_Float16*)(ws + off); off += (size_t)BATCH * TSEQ * HID * 2;
    _Float16* wqkv_h = (_Float16*)(ws + off); off += (size_t)3 * HID * HID * 2;
    _Float16* wout_h = (_Float16*)(ws + off); off += (size_t)HID * HID * 2;
    _Float16* Qh     = (_Float16*)(ws + off); off += (size_t)BATCH * NH * TSEQ * HD * 2;
    _Float16* Kh     = (_Float16*)(ws + off); off += (size_t)BATCH * NH * TSEQ * HD * 2;
    _Float16* Vh     = (_Float16*)(ws + off); off += (size_t)BATCH * NH * TSEQ * HD * 2;
    _Float16* At     = (_Float16*)(ws + off); off += (size_t)BATCH * TSEQ * HID * 2;

    const int n4_hs   = BATCH * TSEQ * HID / 4;
    const int n4_wqkv = 3 * HID * HID / 4;
    const int n4_wout = HID * HID / 4;
    const int n4_all  = n4_hs + n4_wqkv + n4_wout;
    cast_all<<<dim3((n4_all + 255) / 256), dim3(256), 0, stream>>>(
        (const float4*)hs, (const float4*)wqkv, (const float4*)wout,
        (f16x4*)hs_h, (f16x4*)wqkv_h, (f16x4*)wout_h, n4_hs, n4_wqkv, n4_wout);

    // GEMM1: M=4096, N=6144: BM=256 -> grid 16x48 = 768 blocks
    gemm_big<0><<<dim3(768), dim3(512), 0, stream>>>(
        hs_h, wqkv_h, nullptr, Qh, Kh, Vh, 48);

    attn_fwd<<<dim3(512), dim3(256), 0, stream>>>(Qh, Kh, Vh, At);

    // GEMM2: M=4096, N=2048: 128^2 -> grid 32x16 = 512 blocks
    gemm_small<1><<<dim3(512), dim3(256), 0, stream>>>(
        At, wout_h, (float*)d_out, 16);
}